// Round 6
// baseline (290.196 us; speedup 1.0000x reference)
//
#include <hip/hip_runtime.h>
#include <stdint.h>

// ---------------------------------------------------------------------------
// LatticeCNN on MI355X — round 6.
//
// Math (validated rounds 2-5):
//   out(x,y) = leaky( X[x,y]·W1[clsx][clsy] + P2 + P3 + P4 + bias )
//   P3 = prefix_a of V[a][y] = X[24+a,y]·AS[a][py]
//   P2 = prefix_b of U[b][x] = X[x,24+b]·SB[px][b]
//   P4 = 2D prefix of T[a][b] = X[24+a,24+b]·mw[a][b]
//
// Round-5 post-mortem: prep_weights3 was 63us — loads strided 32KB/lane
// (bad thread mapping into mwT) and 3x write amplification (2B stores at
// stride F). Round-6: two-stage prep. Stage A reads original [ab][f*G+g]
// coalesced and writes Int[slot][f][g] coalesced (same orientation, no
// transpose). Stage B batch-transposes Int -> Wall[slot][g][f] via 32x32
// LDS tiles (both sides coalesced). transpose_w4 deleted.
//
// Workspace (256MB avail; ~85MB used):
//   Xt0@0 (8.4) | A1@9 (16.8) | Wall0@26 (6.8) | Wall1@33 (13.7)
//   Int0@47 (6.8) | Int1@54 (13.7) | Out2@68 (16.8) | bias/flag@85
//   V/U/T (18.9MB fp32) in d_out; dead before the final transpose.
// ---------------------------------------------------------------------------

typedef __attribute__((ext_vector_type(8))) short short8;
typedef __attribute__((ext_vector_type(4))) float floatx4;

__device__ __forceinline__ float bf2f(unsigned short u) {
  union { uint32_t u; float f; } c; c.u = ((uint32_t)u) << 16; return c.f;
}
__device__ __forceinline__ unsigned short f2bf(float f) {
  union { float f; uint32_t u; } c; c.f = f;
  uint32_t u = c.u;
  uint32_t r = (u + 0x7FFFu + ((u >> 16) & 1u)) >> 16;
  return (unsigned short)r;
}

// Detect bf16 (flag=0) vs fp32 (flag=1) from x's bit patterns; compute bias.
__global__ void detect_and_bias(const unsigned short* __restrict__ xa,
                                const void* __restrict__ mb0,
                                const void* __restrict__ jb0,
                                const void* __restrict__ mb1,
                                const void* __restrict__ jb1,
                                float* __restrict__ bias0,
                                float* __restrict__ bias1,
                                int* __restrict__ flag) {
  __shared__ int cnt;
  if (threadIdx.x == 0) cnt = 0;
  __syncthreads();
  unsigned short v = xa[threadIdx.x];
  int e = (v >> 7) & 0xFF;
  int ok = (v == 0) || (e >= 110 && e <= 140);
  atomicAdd(&cnt, ok);
  __syncthreads();
  int fp32 = (cnt >= 240) ? 0 : 1;
  if (threadIdx.x == 0) *flag = fp32;
  int g = threadIdx.x & 127;
  const void* mb = (threadIdx.x < 128) ? mb0 : mb1;
  const void* jb = (threadIdx.x < 128) ? jb0 : jb1;
  float* bo = (threadIdx.x < 128) ? bias0 : bias1;
  float m = fp32 ? ((const float*)mb)[g] : bf2f(((const unsigned short*)mb)[g]);
  float j = fp32 ? ((const float*)jb)[g] : bf2f(((const unsigned short*)jb)[g]);
  bo[g] = 0.5f * (m + j);
}

// Transpose src[R][C] -> dst[C][R]; src fp32 or bf16 per flag, dst bf16.
__global__ __launch_bounds__(256) void transpose_in(
    const unsigned short* __restrict__ s16, const float* __restrict__ s32,
    unsigned short* __restrict__ dst, int R, int C,
    const int* __restrict__ flag) {
  __shared__ unsigned short tile[32][33];
  int fp32 = *flag;
  int tx = threadIdx.x, ty = threadIdx.y;
  int c0 = blockIdx.x * 32, r0 = blockIdx.y * 32;
  if (fp32) {
#pragma unroll
    for (int i = 0; i < 32; i += 8)
      tile[ty + i][tx] = f2bf(s32[(size_t)(r0 + ty + i) * C + (c0 + tx)]);
  } else {
#pragma unroll
    for (int i = 0; i < 32; i += 8)
      tile[ty + i][tx] = s16[(size_t)(r0 + ty + i) * C + (c0 + tx)];
  }
  __syncthreads();
#pragma unroll
  for (int i = 0; i < 32; i += 8)
    dst[(size_t)(c0 + ty + i) * R + (r0 + tx)] = tile[tx][ty + i];
}

// Transpose src[R][C] (bf16) -> dst[C][R]; dst fp32 or bf16 per flag.
__global__ __launch_bounds__(256) void transpose_out(
    const unsigned short* __restrict__ src, unsigned short* __restrict__ d16,
    float* __restrict__ d32, int R, int C, const int* __restrict__ flag) {
  __shared__ unsigned short tile[32][33];
  int fp32 = *flag;
  int tx = threadIdx.x, ty = threadIdx.y;
  int c0 = blockIdx.x * 32, r0 = blockIdx.y * 32;
#pragma unroll
  for (int i = 0; i < 32; i += 8)
    tile[ty + i][tx] = src[(size_t)(r0 + ty + i) * C + (c0 + tx)];
  __syncthreads();
  if (fp32) {
#pragma unroll
    for (int i = 0; i < 32; i += 8)
      d32[(size_t)(c0 + ty + i) * R + (r0 + tx)] = bf2f(tile[tx][ty + i]);
  } else {
#pragma unroll
    for (int i = 0; i < 32; i += 8)
      d16[(size_t)(c0 + ty + i) * R + (r0 + tx)] = tile[tx][ty + i];
  }
}

// Weight slot bases inside Int/Wall [slot][...]
#define SLOT_W1 0    // 225 combined pointwise slots (clsx*15+clsy)
#define SLOT_SB 225  // 64 slots (px*8+b)
#define SLOT_AS 289  // 64 slots (a*8+py)
#define SLOT_M  353  // 64 slots (a*8+b)
#define N_SLOTS 417

// Stage A: transforms in the ORIGINAL orientation. Thread = fg index.
// Loads mw/jw[ab*FG+fg] coalesced; stores Int[slot*FG+fg] coalesced.
// grid (64, 4 groups, 2 layers); layer0 blocks with fg>=8192 exit.
__global__ __launch_bounds__(256) void prep_stageA(
    const void* __restrict__ mw0, const void* __restrict__ jw0,
    const void* __restrict__ mw1, const void* __restrict__ jw1,
    unsigned short* __restrict__ Int0, unsigned short* __restrict__ Int1,
    const int* __restrict__ flag) {
  int layer = blockIdx.z;
  int FG = layer ? 16384 : 8192;
  int fg = blockIdx.x * 256 + threadIdx.x;
  if (fg >= FG) return;
  int fp32 = *flag;
  const void* mw = layer ? mw1 : mw0;
  unsigned short* Int = layer ? Int1 : Int0;
  int group = blockIdx.y;

  float w[64];
#pragma unroll
  for (int ab = 0; ab < 64; ++ab) {
    size_t idx = (size_t)ab * FG + fg;
    w[ab] = fp32 ? ((const float*)mw)[idx]
                 : bf2f(((const unsigned short*)mw)[idx]);
  }
  if (group == 3) {  // raw meet weights
#pragma unroll
    for (int ab = 0; ab < 64; ++ab)
      Int[(size_t)(SLOT_M + ab) * FG + fg] = f2bf(0.5f * w[ab]);
    return;
  }
  // suffix along b -> AS[a][py]
#pragma unroll
  for (int a = 0; a < 8; ++a)
#pragma unroll
    for (int b = 6; b >= 0; --b) w[a * 8 + b] += w[a * 8 + b + 1];
  if (group == 2) {
#pragma unroll
    for (int ab = 0; ab < 64; ++ab)
      Int[(size_t)(SLOT_AS + ab) * FG + fg] = f2bf(0.5f * w[ab]);
  }
  // suffix along a -> SS[px][py]
#pragma unroll
  for (int a = 6; a >= 0; --a)
#pragma unroll
    for (int b = 0; b < 8; ++b) w[a * 8 + b] += w[(a + 1) * 8 + b];
  if (group == 2) {  // SB[px][b] = SS[px][b] - SS[px][b+1]
#pragma unroll
    for (int px = 0; px < 8; ++px)
#pragma unroll
      for (int b = 0; b < 8; ++b) {
        float v = w[px * 8 + b] - (b < 7 ? w[px * 8 + b + 1] : 0.0f);
        Int[(size_t)(SLOT_SB + px * 8 + b) * FG + fg] = f2bf(0.5f * v);
      }
    return;
  }
  // groups 0,1: join prefix sums + combined W1 (split by cx halves)
  const void* jw = layer ? jw1 : jw0;
  float pp[64];
#pragma unroll
  for (int ab = 0; ab < 64; ++ab) {
    size_t idx = (size_t)ab * FG + fg;
    pp[ab] = fp32 ? ((const float*)jw)[idx]
                  : bf2f(((const unsigned short*)jw)[idx]);
  }
#pragma unroll
  for (int a = 0; a < 8; ++a)
#pragma unroll
    for (int b = 1; b < 8; ++b) pp[a * 8 + b] += pp[a * 8 + b - 1];
#pragma unroll
  for (int a = 1; a < 8; ++a)
#pragma unroll
    for (int b = 0; b < 8; ++b) pp[a * 8 + b] += pp[(a - 1) * 8 + b];
  int cx0 = (group == 0) ? 0 : 7, cx1 = (group == 0) ? 7 : 15;
  for (int cx = cx0; cx < cx1; ++cx) {
    int pmx = cx < 7 ? cx : 7;
    int pxx = cx > 7 ? cx - 7 : 0;
#pragma unroll
    for (int cy = 0; cy < 15; ++cy) {
      int pmy = cy < 7 ? cy : 7;
      int pyy = cy > 7 ? cy - 7 : 0;
      float v = 0.5f * (w[pxx * 8 + pyy] + pp[pmx * 8 + pmy]);
      Int[(size_t)(SLOT_W1 + cx * 15 + cy) * FG + fg] = f2bf(v);
    }
  }
}

// Stage B: per-slot 32x32 tile transpose Int[slot][f][g] -> Wall[slot][g][f].
// grid (4 g-tiles, 4 f-tiles, 834 = slot + 417*layer); tb (32,8).
__global__ __launch_bounds__(256) void prep_stageB(
    const unsigned short* __restrict__ Int0,
    const unsigned short* __restrict__ Int1,
    unsigned short* __restrict__ Wall0, unsigned short* __restrict__ Wall1) {
  int zz = blockIdx.z;
  int layer = (zz >= N_SLOTS) ? 1 : 0;
  int slot = zz - layer * N_SLOTS;
  int F = layer ? 128 : 64;
  int f0 = blockIdx.y * 32;
  if (f0 >= F) return;
  int g0 = blockIdx.x * 32;
  const unsigned short* src =
      (layer ? Int1 : Int0) + (size_t)slot * F * 128;
  unsigned short* dst = (layer ? Wall1 : Wall0) + (size_t)slot * F * 128;
  __shared__ unsigned short tile[32][33];
  int tx = threadIdx.x, ty = threadIdx.y;
#pragma unroll
  for (int i = 0; i < 32; i += 8)
    tile[ty + i][tx] = src[(size_t)(f0 + ty + i) * 128 + (g0 + tx)];
  __syncthreads();
#pragma unroll
  for (int i = 0; i < 32; i += 8)
    dst[(size_t)(g0 + ty + i) * F + (f0 + tx)] = tile[tx][ty + i];
}

// MFMA core: acc[64m x (16*NT)g] += A[64m x F] * Wt[g x F]^T (W pre-offset).
// A fragment: lane holds A[m=lane&15][k=(lane>>4)*8+j]   (16B load)
// B fragment: lane holds Wt[n=lane&15][k=(lane>>4)*8+j]  (16B load)
template <int F, int NT>
__device__ __forceinline__ void mfma_tile(
    const unsigned short* __restrict__ A, const unsigned short* __restrict__ W,
    floatx4 acc[NT], int wave, int n, int q) {
  const unsigned short* a_ptr = A + ((size_t)(wave * 16 + n)) * F + q * 8;
  const unsigned short* w_ptr = W + (size_t)n * F + q * 8;
#pragma unroll
  for (int kk = 0; kk < F; kk += 32) {
    short8 av = *(const short8*)(a_ptr + kk);
#pragma unroll
    for (int t = 0; t < NT; ++t) {
      short8 bv = *(const short8*)(w_ptr + (size_t)t * 16 * F + kk);
      acc[t] = __builtin_amdgcn_mfma_f32_16x16x32_bf16(av, bv, acc[t], 0, 0, 0);
    }
  }
}

// Correction matmuls: grid (576, 2); gs = g-half. Plain fp32 stores.
//   bid <256 : V[a][y] = X[24+a, y]      * AS[a][py(y)]
//   bid <512 : U[b][x] = X[x, 24+b]      * SB[px(x)][b]
//   else     : T[a][b] = X[24+a, 24+b]   * mw[a][b]
template <int F>
__global__ __launch_bounds__(256) void corr_gemm(
    const unsigned short* __restrict__ Xt, const unsigned short* __restrict__ Wall,
    float* __restrict__ V, float* __restrict__ U, float* __restrict__ T) {
  int bid = blockIdx.x, gs = blockIdx.y;
  int wave = threadIdx.x >> 6, lane = threadIdx.x & 63;
  int n = lane & 15, q = lane >> 4;
  int ipos, slot;
  float* out;
  if (bid < 256) {
    int a = bid >> 5, y = bid & 31;
    int py = y > 24 ? y - 24 : 0;
    ipos = (24 + a) * 32 + y;
    slot = SLOT_AS + a * 8 + py;
    out = V + (size_t)(a * 32 + y) * 8192;
  } else if (bid < 512) {
    int i = bid - 256;
    int b = i >> 5, x = i & 31;
    int px = x > 24 ? x - 24 : 0;
    ipos = x * 32 + 24 + b;
    slot = SLOT_SB + px * 8 + b;
    out = U + (size_t)(b * 32 + x) * 8192;
  } else {
    int i = bid - 512;
    int a = i >> 3, b = i & 7;
    ipos = (24 + a) * 32 + 24 + b;
    slot = SLOT_M + a * 8 + b;
    out = T + (size_t)(a * 8 + b) * 8192;
  }
  floatx4 acc[4];
#pragma unroll
  for (int t = 0; t < 4; ++t) acc[t] = (floatx4){0.f, 0.f, 0.f, 0.f};
  mfma_tile<F, 4>(Xt + (size_t)ipos * 64 * F,
                  Wall + ((size_t)slot * 128 + gs * 64) * F, acc, wave, n, q);
#pragma unroll
  for (int t = 0; t < 4; ++t) {
    int gcol = gs * 64 + t * 16 + n;
#pragma unroll
    for (int r = 0; r < 4; ++r) {
      int m = wave * 16 + q * 4 + r;
      out[(size_t)m * 128 + gcol] = acc[t][r];
    }
  }
}

// In-place prefix scans: [0,1024) P3 over V (a); [1024,2048) P2 over U (b);
// [2048,2080) 2D prefix over T (a,b).
__global__ __launch_bounds__(256) void scan_corr(float* __restrict__ V,
                                                 float* __restrict__ U,
                                                 float* __restrict__ T) {
  int b = blockIdx.x;
  if (b < 2048) {
    float* base = (b < 1024) ? V : U;
    int tid = ((b & 1023) * 256 + threadIdx.x);  // (y|x, mg): 262144
    float* p = base + (size_t)tid;               // stride 262144 over a|b
    float s = 0.f;
#pragma unroll
    for (int a = 0; a < 8; ++a) {
      s += p[(size_t)a * 262144];
      p[(size_t)a * 262144] = s;
    }
  } else {
    int mg = (b - 2048) * 256 + threadIdx.x;  // 8192
    float col[8];
#pragma unroll
    for (int i = 0; i < 8; ++i) col[i] = 0.f;
#pragma unroll
    for (int a = 0; a < 8; ++a) {
      float rs = 0.f;
#pragma unroll
      for (int bb = 0; bb < 8; ++bb) {
        size_t idx = (size_t)(a * 8 + bb) * 8192 + mg;
        col[bb] += T[idx];
        rs += col[bb];
        T[idx] = rs;
      }
    }
  }
}

// term1 + corrections + bias + leaky-relu -> bf16 [pos][m][128].
// grid (1024, 2); gs = g-half. Correction/bias loads hoisted before MFMA.
template <int F>
__global__ __launch_bounds__(256) void final_gemm(
    const unsigned short* __restrict__ Xt, const unsigned short* __restrict__ Wall,
    const float* __restrict__ V, const float* __restrict__ U,
    const float* __restrict__ T, const float* __restrict__ bias,
    unsigned short* __restrict__ Out) {
  int pos = blockIdx.x, gs = blockIdx.y;
  int x = pos >> 5, y = pos & 31;
  int wave = threadIdx.x >> 6, lane = threadIdx.x & 63;
  int n = lane & 15, q = lane >> 4;
  int clsx = x < 7 ? x : (x <= 24 ? 7 : x - 17);
  int clsy = y < 7 ? y : (y <= 24 ? 7 : y - 17);
  int px = x > 24 ? x - 24 : 0;
  int py = y > 24 ? y - 24 : 0;
  const float* c3 = px ? V + ((size_t)(px - 1) * 32 + y) * 8192 : nullptr;
  const float* c2 = py ? U + ((size_t)(py - 1) * 32 + x) * 8192 : nullptr;
  const float* c4 =
      (px && py) ? T + (size_t)((px - 1) * 8 + (py - 1)) * 8192 : nullptr;

  // Hoisted bias + correction sum (loads overlap the MFMA-loop loads).
  float csum[4][4];
#pragma unroll
  for (int t = 0; t < 4; ++t) {
    int gcol = gs * 64 + t * 16 + n;
    float bv = bias[gcol];
#pragma unroll
    for (int r = 0; r < 4; ++r) {
      int m = wave * 16 + q * 4 + r;
      size_t idx = (size_t)m * 128 + gcol;
      float v = bv;
      if (c3) v += c3[idx];
      if (c2) v += c2[idx];
      if (c4) v += c4[idx];
      csum[t][r] = v;
    }
  }

  floatx4 acc[4];
#pragma unroll
  for (int t = 0; t < 4; ++t) acc[t] = (floatx4){0.f, 0.f, 0.f, 0.f};
  mfma_tile<F, 4>(Xt + (size_t)pos * 64 * F,
                  Wall + ((size_t)(SLOT_W1 + clsx * 15 + clsy) * 128 + gs * 64) * F,
                  acc, wave, n, q);

  unsigned short* o = Out + (size_t)pos * 64 * 128;
#pragma unroll
  for (int t = 0; t < 4; ++t) {
    int gcol = gs * 64 + t * 16 + n;
#pragma unroll
    for (int r = 0; r < 4; ++r) {
      int m = wave * 16 + q * 4 + r;  // C/D layout: row=(lane>>4)*4+reg
      float v = acc[t][r] + csum[t][r];
      v = v > 0.f ? v : 0.01f * v;
      o[(size_t)m * 128 + gcol] = f2bf(v);
    }
  }
}

extern "C" void kernel_launch(void* const* d_in, const int* in_sizes, int n_in,
                              void* d_out, int out_size, void* d_ws,
                              size_t ws_size, hipStream_t stream) {
  const void* x   = d_in[0];
  const void* mw0 = d_in[5];
  const void* mb0 = d_in[6];
  const void* jw0 = d_in[7];
  const void* jb0 = d_in[8];
  const void* mw1 = d_in[9];
  const void* mb1 = d_in[10];
  const void* jw1 = d_in[11];
  const void* jb1 = d_in[12];

  char* ws = (char*)d_ws;
  const size_t MB = 1u << 20;
  unsigned short* Xt0   = (unsigned short*)(ws + 0);        // 8.4 MB
  unsigned short* A1    = (unsigned short*)(ws + 9 * MB);   // 16.8 MB
  unsigned short* Wall0 = (unsigned short*)(ws + 26 * MB);  // 6.8 MB
  unsigned short* Wall1 = (unsigned short*)(ws + 33 * MB);  // 13.7 MB
  unsigned short* Int0  = (unsigned short*)(ws + 47 * MB);  // 6.8 MB
  unsigned short* Int1  = (unsigned short*)(ws + 54 * MB);  // 13.7 MB
  unsigned short* Out2  = (unsigned short*)(ws + 68 * MB);  // 16.8 MB
  float* bias0 = (float*)(ws + 85 * MB);
  float* bias1 = bias0 + 128;
  int*   flag  = (int*)(bias1 + 128);
  // Corrections in d_out (>=18.9MB): V 8.39 | U 8.39 | T 2.1 (MB, fp32)
  float* V = (float*)d_out;
  float* U = V + (size_t)8 * 32 * 8192;
  float* T = U + (size_t)8 * 32 * 8192;

  dim3 tb(32, 8);
  detect_and_bias<<<1, 256, 0, stream>>>((const unsigned short*)x, mb0, jb0,
                                         mb1, jb1, bias0, bias1, flag);
  prep_stageA<<<dim3(64, 4, 2), 256, 0, stream>>>(mw0, jw0, mw1, jw1, Int0,
                                                  Int1, flag);
  prep_stageB<<<dim3(4, 4, 2 * N_SLOTS), tb, 0, stream>>>(Int0, Int1, Wall0,
                                                          Wall1);
  // x [m*64+f=4096][pos=1024] -> Xt0 [pos][m][f]
  transpose_in<<<dim3(32, 128), tb, 0, stream>>>(
      (const unsigned short*)x, (const float*)x, Xt0, 4096, 1024, flag);

  // ---- Layer 1 (F=64) ----
  corr_gemm<64><<<dim3(576, 2), 256, 0, stream>>>(Xt0, Wall0, V, U, T);
  scan_corr<<<2080, 256, 0, stream>>>(V, U, T);
  final_gemm<64><<<dim3(1024, 2), 256, 0, stream>>>(Xt0, Wall0, V, U, T,
                                                    bias0, A1);
  // ---- Layer 2 (F=128) ----
  corr_gemm<128><<<dim3(576, 2), 256, 0, stream>>>(A1, Wall1, V, U, T);
  scan_corr<<<2080, 256, 0, stream>>>(V, U, T);
  final_gemm<128><<<dim3(1024, 2), 256, 0, stream>>>(A1, Wall1, V, U, T,
                                                     bias1, Out2);

  // Out2 [pos=1024][m*128+g=8192] -> d_out [m][g][pos] (V/U/T dead)
  transpose_out<<<dim3(256, 32), tb, 0, stream>>>(
      Out2, (unsigned short*)d_out, (float*)d_out, 1024, 8192, flag);
}

// Round 7
// 272.183 us; speedup vs baseline: 1.0662x; 1.0662x over previous
//
#include <hip/hip_runtime.h>
#include <stdint.h>

// ---------------------------------------------------------------------------
// LatticeCNN on MI355X — round 7.
//
// Math (validated rounds 2-6):
//   out(x,y) = leaky( X[x,y]·W1[clsx][clsy] + P2 + P3 + P4 + bias )
//   P3 = prefix_a of V[a][y] = X[24+a,y]·AS[a][py]
//   P2 = prefix_b of U[b][x] = X[x,24+b]·SB[px][b]
//   P4 = 2D prefix of T[a][b] = X[24+a,24+b]·mw[a][b]
//
// Round-6 post-mortem: prep_stageA was REGISTER-SPILL bound (w[64]+pp[64]
// fp32 arrays = 128+ VGPRs at VGPR_Count=132; WRITE_SIZE 67MB vs 20.5 ideal
// = scratch round-trips). Round-5 had the same disease. Round-7: weight
// tables are linear maps over the 64 ab-taps -> prep becomes an MFMA GEMM:
//   Int[slot][fg] = sum_k L[slot][k] * PB[fg][k],  K = 128 = [mw ; jw]
// with L a closed-form 0/0.5 coefficient matrix (448 padded slots):
//   W1(cx,cy): Lm=0.5[a>=pxx][b>=pyy], Lj=0.5[a<=pmx][b<=pmy]
//   SB(px,b0): Lm=0.5[a>=px][b==b0] ;  AS(a0,py): Lm=0.5[a==a0][b>=py]
//   M (a0,b0): Lm=0.5[a==a0][b==b0]
// pack_weights transposes mw||jw -> PB[fg][128] bf16 (coalesced both ways);
// prep_gemm reuses the validated mfma_tile fragments (no arrays, no spill).
//
// Workspace (~96MB of 256MB):
//   Xt0@0 (8.4) | A1@9 (16.8) | Wall0@26 (6.8) | Wall1@33 (13.7)
//   Int0@47 (7.4, 448 slots) | Int1@55 (14.7) | Out2@70 (16.8)
//   bias/flag@87 | PB0@88 (2.1) | PB1@91 (4.2) | L@96 (0.11)
//   V/U/T (18.9MB fp32) in d_out; dead before the final transpose.
// ---------------------------------------------------------------------------

typedef __attribute__((ext_vector_type(8))) short short8;
typedef __attribute__((ext_vector_type(4))) float floatx4;

__device__ __forceinline__ float bf2f(unsigned short u) {
  union { uint32_t u; float f; } c; c.u = ((uint32_t)u) << 16; return c.f;
}
__device__ __forceinline__ unsigned short f2bf(float f) {
  union { float f; uint32_t u; } c; c.f = f;
  uint32_t u = c.u;
  uint32_t r = (u + 0x7FFFu + ((u >> 16) & 1u)) >> 16;
  return (unsigned short)r;
}

// Detect bf16 (flag=0) vs fp32 (flag=1) from x's bit patterns; compute bias.
__global__ void detect_and_bias(const unsigned short* __restrict__ xa,
                                const void* __restrict__ mb0,
                                const void* __restrict__ jb0,
                                const void* __restrict__ mb1,
                                const void* __restrict__ jb1,
                                float* __restrict__ bias0,
                                float* __restrict__ bias1,
                                int* __restrict__ flag) {
  __shared__ int cnt;
  if (threadIdx.x == 0) cnt = 0;
  __syncthreads();
  unsigned short v = xa[threadIdx.x];
  int e = (v >> 7) & 0xFF;
  int ok = (v == 0) || (e >= 110 && e <= 140);
  atomicAdd(&cnt, ok);
  __syncthreads();
  int fp32 = (cnt >= 240) ? 0 : 1;
  if (threadIdx.x == 0) *flag = fp32;
  int g = threadIdx.x & 127;
  const void* mb = (threadIdx.x < 128) ? mb0 : mb1;
  const void* jb = (threadIdx.x < 128) ? jb0 : jb1;
  float* bo = (threadIdx.x < 128) ? bias0 : bias1;
  float m = fp32 ? ((const float*)mb)[g] : bf2f(((const unsigned short*)mb)[g]);
  float j = fp32 ? ((const float*)jb)[g] : bf2f(((const unsigned short*)jb)[g]);
  bo[g] = 0.5f * (m + j);
}

// Transpose src[R][C] -> dst[C][R]; src fp32 or bf16 per flag, dst bf16.
__global__ __launch_bounds__(256) void transpose_in(
    const unsigned short* __restrict__ s16, const float* __restrict__ s32,
    unsigned short* __restrict__ dst, int R, int C,
    const int* __restrict__ flag) {
  __shared__ unsigned short tile[32][33];
  int fp32 = *flag;
  int tx = threadIdx.x, ty = threadIdx.y;
  int c0 = blockIdx.x * 32, r0 = blockIdx.y * 32;
  if (fp32) {
#pragma unroll
    for (int i = 0; i < 32; i += 8)
      tile[ty + i][tx] = f2bf(s32[(size_t)(r0 + ty + i) * C + (c0 + tx)]);
  } else {
#pragma unroll
    for (int i = 0; i < 32; i += 8)
      tile[ty + i][tx] = s16[(size_t)(r0 + ty + i) * C + (c0 + tx)];
  }
  __syncthreads();
#pragma unroll
  for (int i = 0; i < 32; i += 8)
    dst[(size_t)(c0 + ty + i) * R + (r0 + tx)] = tile[tx][ty + i];
}

// Transpose src[R][C] (bf16) -> dst[C][R]; dst fp32 or bf16 per flag.
__global__ __launch_bounds__(256) void transpose_out(
    const unsigned short* __restrict__ src, unsigned short* __restrict__ d16,
    float* __restrict__ d32, int R, int C, const int* __restrict__ flag) {
  __shared__ unsigned short tile[32][33];
  int fp32 = *flag;
  int tx = threadIdx.x, ty = threadIdx.y;
  int c0 = blockIdx.x * 32, r0 = blockIdx.y * 32;
#pragma unroll
  for (int i = 0; i < 32; i += 8)
    tile[ty + i][tx] = src[(size_t)(r0 + ty + i) * C + (c0 + tx)];
  __syncthreads();
  if (fp32) {
#pragma unroll
    for (int i = 0; i < 32; i += 8)
      d32[(size_t)(c0 + ty + i) * R + (r0 + tx)] = bf2f(tile[tx][ty + i]);
  } else {
#pragma unroll
    for (int i = 0; i < 32; i += 8)
      d16[(size_t)(c0 + ty + i) * R + (r0 + tx)] = tile[tx][ty + i];
  }
}

// Weight slot bases inside Int/Wall [slot][...]
#define SLOT_W1 0    // 225 combined pointwise slots (clsx*15+clsy)
#define SLOT_SB 225  // 64 slots (px*8+b)
#define SLOT_AS 289  // 64 slots (a*8+py)
#define SLOT_M  353  // 64 slots (a*8+b)
#define N_SLOTS 417
#define N_SLOTS_PAD 448

// Pack mw||jw -> PB[fg][128] bf16 via 32x32 LDS tiles.
// grid (FG/32 max=512, 4 k-tiles, 2 layers); kt 0,1 = mw, 2,3 = jw.
__global__ __launch_bounds__(256) void pack_weights(
    const void* __restrict__ mw0, const void* __restrict__ jw0,
    const void* __restrict__ mw1, const void* __restrict__ jw1,
    unsigned short* __restrict__ PB0, unsigned short* __restrict__ PB1,
    const int* __restrict__ flag) {
  int layer = blockIdx.z;
  int FG = layer ? 16384 : 8192;
  int c0 = blockIdx.x * 32;  // fg base
  if (c0 >= FG) return;
  int kt = blockIdx.y;
  const void* src = (kt < 2) ? (layer ? mw1 : mw0) : (layer ? jw1 : jw0);
  unsigned short* PB = layer ? PB1 : PB0;
  int r0 = (kt & 1) * 32;  // ab row base
  int fp32 = *flag;
  __shared__ unsigned short tile[32][33];
  int tx = threadIdx.x, ty = threadIdx.y;
#pragma unroll
  for (int i = 0; i < 32; i += 8) {
    size_t idx = (size_t)(r0 + ty + i) * FG + (c0 + tx);
    tile[ty + i][tx] = fp32 ? f2bf(((const float*)src)[idx])
                            : ((const unsigned short*)src)[idx];
  }
  __syncthreads();
#pragma unroll
  for (int i = 0; i < 32; i += 8)
    PB[(size_t)(c0 + ty + i) * 128 + (kt * 32 + tx)] = tile[tx][ty + i];
}

// Closed-form coefficient matrix L[448][128] bf16 (rows >=417 zero).
__global__ __launch_bounds__(256) void build_L(unsigned short* __restrict__ L) {
  int tid = blockIdx.x * 256 + threadIdx.x;  // 448*128 = 57344
  int slot = tid >> 7, k = tid & 127;
  int isj = k >= 64, ab = k & 63, a = ab >> 3, b = ab & 7;
  float v = 0.f;
  if (slot < 225) {
    int cx = slot / 15, cy = slot % 15;
    int pmx = cx < 7 ? cx : 7, pxx = cx > 7 ? cx - 7 : 0;
    int pmy = cy < 7 ? cy : 7, pyy = cy > 7 ? cy - 7 : 0;
    if (!isj) v = (a >= pxx && b >= pyy) ? 0.5f : 0.f;
    else      v = (a <= pmx && b <= pmy) ? 0.5f : 0.f;
  } else if (slot < 289) {
    int s = slot - SLOT_SB, px = s >> 3, b0 = s & 7;
    if (!isj) v = (a >= px && b == b0) ? 0.5f : 0.f;
  } else if (slot < 353) {
    int s = slot - SLOT_AS, a0 = s >> 3, py = s & 7;
    if (!isj) v = (a == a0 && b >= py) ? 0.5f : 0.f;
  } else if (slot < 417) {
    int s = slot - SLOT_M, a0 = s >> 3, b0 = s & 7;
    if (!isj) v = (a == a0 && b == b0) ? 0.5f : 0.f;
  }
  L[tid] = f2bf(v);
}

// MFMA core: acc[64m x (16*NT)g] += A[64m x F] * Wt[g x F]^T (W pre-offset).
// A fragment: lane holds A[m=lane&15][k=(lane>>4)*8+j]   (16B load)
// B fragment: lane holds Wt[n=lane&15][k=(lane>>4)*8+j]  (16B load)
template <int F, int NT>
__device__ __forceinline__ void mfma_tile(
    const unsigned short* __restrict__ A, const unsigned short* __restrict__ W,
    floatx4 acc[NT], int wave, int n, int q) {
  const unsigned short* a_ptr = A + ((size_t)(wave * 16 + n)) * F + q * 8;
  const unsigned short* w_ptr = W + (size_t)n * F + q * 8;
#pragma unroll
  for (int kk = 0; kk < F; kk += 32) {
    short8 av = *(const short8*)(a_ptr + kk);
#pragma unroll
    for (int t = 0; t < NT; ++t) {
      short8 bv = *(const short8*)(w_ptr + (size_t)t * 16 * F + kk);
      acc[t] = __builtin_amdgcn_mfma_f32_16x16x32_bf16(av, bv, acc[t], 0, 0, 0);
    }
  }
}

// Prep GEMM: Int[slot][fg] = sum_k L[slot][k]*PB[fg][k].
// grid (n-tiles of 128 fg, 7 m-tiles of 64 slots, 2 layers).
__global__ __launch_bounds__(256) void prep_gemm(
    const unsigned short* __restrict__ L,
    const unsigned short* __restrict__ PB0,
    const unsigned short* __restrict__ PB1,
    unsigned short* __restrict__ Int0, unsigned short* __restrict__ Int1) {
  int layer = blockIdx.z;
  int FG = layer ? 16384 : 8192;
  int n0 = blockIdx.x * 128;
  if (n0 >= FG) return;
  int m0 = blockIdx.y * 64;
  const unsigned short* PB = layer ? PB1 : PB0;
  unsigned short* Int = layer ? Int1 : Int0;
  int wave = threadIdx.x >> 6, lane = threadIdx.x & 63;
  int n = lane & 15, q = lane >> 4;
  floatx4 acc[8];
#pragma unroll
  for (int t = 0; t < 8; ++t) acc[t] = (floatx4){0.f, 0.f, 0.f, 0.f};
  mfma_tile<128, 8>(L + (size_t)m0 * 128, PB + (size_t)n0 * 128, acc, wave, n, q);
#pragma unroll
  for (int t = 0; t < 8; ++t) {
    int gcol = n0 + t * 16 + n;
#pragma unroll
    for (int r = 0; r < 4; ++r) {
      int m = m0 + wave * 16 + q * 4 + r;  // C/D: row=(lane>>4)*4+reg
      Int[(size_t)m * FG + gcol] = f2bf(acc[t][r]);
    }
  }
}

// Stage B: per-slot 32x32 tile transpose Int[slot][f][g] -> Wall[slot][g][f].
__global__ __launch_bounds__(256) void prep_stageB(
    const unsigned short* __restrict__ Int0,
    const unsigned short* __restrict__ Int1,
    unsigned short* __restrict__ Wall0, unsigned short* __restrict__ Wall1) {
  int zz = blockIdx.z;
  int layer = (zz >= N_SLOTS) ? 1 : 0;
  int slot = zz - layer * N_SLOTS;
  int F = layer ? 128 : 64;
  int f0 = blockIdx.y * 32;
  if (f0 >= F) return;
  int g0 = blockIdx.x * 32;
  const unsigned short* src =
      (layer ? Int1 : Int0) + (size_t)slot * F * 128;
  unsigned short* dst = (layer ? Wall1 : Wall0) + (size_t)slot * F * 128;
  __shared__ unsigned short tile[32][33];
  int tx = threadIdx.x, ty = threadIdx.y;
#pragma unroll
  for (int i = 0; i < 32; i += 8)
    tile[ty + i][tx] = src[(size_t)(f0 + ty + i) * 128 + (g0 + tx)];
  __syncthreads();
#pragma unroll
  for (int i = 0; i < 32; i += 8)
    dst[(size_t)(g0 + ty + i) * F + (f0 + tx)] = tile[tx][ty + i];
}

// Correction matmuls: grid (576, 2); gs = g-half. Plain fp32 stores.
//   bid <256 : V[a][y] = X[24+a, y]      * AS[a][py(y)]
//   bid <512 : U[b][x] = X[x, 24+b]      * SB[px(x)][b]
//   else     : T[a][b] = X[24+a, 24+b]   * mw[a][b]
template <int F>
__global__ __launch_bounds__(256) void corr_gemm(
    const unsigned short* __restrict__ Xt, const unsigned short* __restrict__ Wall,
    float* __restrict__ V, float* __restrict__ U, float* __restrict__ T) {
  int bid = blockIdx.x, gs = blockIdx.y;
  int wave = threadIdx.x >> 6, lane = threadIdx.x & 63;
  int n = lane & 15, q = lane >> 4;
  int ipos, slot;
  float* out;
  if (bid < 256) {
    int a = bid >> 5, y = bid & 31;
    int py = y > 24 ? y - 24 : 0;
    ipos = (24 + a) * 32 + y;
    slot = SLOT_AS + a * 8 + py;
    out = V + (size_t)(a * 32 + y) * 8192;
  } else if (bid < 512) {
    int i = bid - 256;
    int b = i >> 5, x = i & 31;
    int px = x > 24 ? x - 24 : 0;
    ipos = x * 32 + 24 + b;
    slot = SLOT_SB + px * 8 + b;
    out = U + (size_t)(b * 32 + x) * 8192;
  } else {
    int i = bid - 512;
    int a = i >> 3, b = i & 7;
    ipos = (24 + a) * 32 + 24 + b;
    slot = SLOT_M + a * 8 + b;
    out = T + (size_t)(a * 8 + b) * 8192;
  }
  floatx4 acc[4];
#pragma unroll
  for (int t = 0; t < 4; ++t) acc[t] = (floatx4){0.f, 0.f, 0.f, 0.f};
  mfma_tile<F, 4>(Xt + (size_t)ipos * 64 * F,
                  Wall + ((size_t)slot * 128 + gs * 64) * F, acc, wave, n, q);
#pragma unroll
  for (int t = 0; t < 4; ++t) {
    int gcol = gs * 64 + t * 16 + n;
#pragma unroll
    for (int r = 0; r < 4; ++r) {
      int m = wave * 16 + q * 4 + r;
      out[(size_t)m * 128 + gcol] = acc[t][r];
    }
  }
}

// In-place prefix scans: [0,1024) P3 over V (a); [1024,2048) P2 over U (b);
// [2048,2080) 2D prefix over T (a,b).
__global__ __launch_bounds__(256) void scan_corr(float* __restrict__ V,
                                                 float* __restrict__ U,
                                                 float* __restrict__ T) {
  int b = blockIdx.x;
  if (b < 2048) {
    float* base = (b < 1024) ? V : U;
    int tid = ((b & 1023) * 256 + threadIdx.x);  // (y|x, mg): 262144
    float* p = base + (size_t)tid;               // stride 262144 over a|b
    float s = 0.f;
#pragma unroll
    for (int a = 0; a < 8; ++a) {
      s += p[(size_t)a * 262144];
      p[(size_t)a * 262144] = s;
    }
  } else {
    int mg = (b - 2048) * 256 + threadIdx.x;  // 8192
    float col[8];
#pragma unroll
    for (int i = 0; i < 8; ++i) col[i] = 0.f;
#pragma unroll
    for (int a = 0; a < 8; ++a) {
      float rs = 0.f;
#pragma unroll
      for (int bb = 0; bb < 8; ++bb) {
        size_t idx = (size_t)(a * 8 + bb) * 8192 + mg;
        col[bb] += T[idx];
        rs += col[bb];
        T[idx] = rs;
      }
    }
  }
}

// term1 + corrections + bias + leaky-relu -> bf16 [pos][m][128].
// grid (1024, 2); gs = g-half. Correction/bias loads hoisted before MFMA.
template <int F>
__global__ __launch_bounds__(256) void final_gemm(
    const unsigned short* __restrict__ Xt, const unsigned short* __restrict__ Wall,
    const float* __restrict__ V, const float* __restrict__ U,
    const float* __restrict__ T, const float* __restrict__ bias,
    unsigned short* __restrict__ Out) {
  int pos = blockIdx.x, gs = blockIdx.y;
  int x = pos >> 5, y = pos & 31;
  int wave = threadIdx.x >> 6, lane = threadIdx.x & 63;
  int n = lane & 15, q = lane >> 4;
  int clsx = x < 7 ? x : (x <= 24 ? 7 : x - 17);
  int clsy = y < 7 ? y : (y <= 24 ? 7 : y - 17);
  int px = x > 24 ? x - 24 : 0;
  int py = y > 24 ? y - 24 : 0;
  const float* c3 = px ? V + ((size_t)(px - 1) * 32 + y) * 8192 : nullptr;
  const float* c2 = py ? U + ((size_t)(py - 1) * 32 + x) * 8192 : nullptr;
  const float* c4 =
      (px && py) ? T + (size_t)((px - 1) * 8 + (py - 1)) * 8192 : nullptr;

  // Hoisted bias + correction sum (loads overlap the MFMA-loop loads).
  float csum[4][4];
#pragma unroll
  for (int t = 0; t < 4; ++t) {
    int gcol = gs * 64 + t * 16 + n;
    float bv = bias[gcol];
#pragma unroll
    for (int r = 0; r < 4; ++r) {
      int m = wave * 16 + q * 4 + r;
      size_t idx = (size_t)m * 128 + gcol;
      float v = bv;
      if (c3) v += c3[idx];
      if (c2) v += c2[idx];
      if (c4) v += c4[idx];
      csum[t][r] = v;
    }
  }

  floatx4 acc[4];
#pragma unroll
  for (int t = 0; t < 4; ++t) acc[t] = (floatx4){0.f, 0.f, 0.f, 0.f};
  mfma_tile<F, 4>(Xt + (size_t)pos * 64 * F,
                  Wall + ((size_t)(SLOT_W1 + clsx * 15 + clsy) * 128 + gs * 64) * F,
                  acc, wave, n, q);

  unsigned short* o = Out + (size_t)pos * 64 * 128;
#pragma unroll
  for (int t = 0; t < 4; ++t) {
    int gcol = gs * 64 + t * 16 + n;
#pragma unroll
    for (int r = 0; r < 4; ++r) {
      int m = wave * 16 + q * 4 + r;  // C/D layout: row=(lane>>4)*4+reg
      float v = acc[t][r] + csum[t][r];
      v = v > 0.f ? v : 0.01f * v;
      o[(size_t)m * 128 + gcol] = f2bf(v);
    }
  }
}

extern "C" void kernel_launch(void* const* d_in, const int* in_sizes, int n_in,
                              void* d_out, int out_size, void* d_ws,
                              size_t ws_size, hipStream_t stream) {
  const void* x   = d_in[0];
  const void* mw0 = d_in[5];
  const void* mb0 = d_in[6];
  const void* jw0 = d_in[7];
  const void* jb0 = d_in[8];
  const void* mw1 = d_in[9];
  const void* mb1 = d_in[10];
  const void* jw1 = d_in[11];
  const void* jb1 = d_in[12];

  char* ws = (char*)d_ws;
  const size_t MB = 1u << 20;
  unsigned short* Xt0   = (unsigned short*)(ws + 0);        // 8.4 MB
  unsigned short* A1    = (unsigned short*)(ws + 9 * MB);   // 16.8 MB
  unsigned short* Wall0 = (unsigned short*)(ws + 26 * MB);  // 6.8 MB
  unsigned short* Wall1 = (unsigned short*)(ws + 33 * MB);  // 13.7 MB
  unsigned short* Int0  = (unsigned short*)(ws + 47 * MB);  // 7.4 MB (448)
  unsigned short* Int1  = (unsigned short*)(ws + 55 * MB);  // 14.7 MB (448)
  unsigned short* Out2  = (unsigned short*)(ws + 70 * MB);  // 16.8 MB
  float* bias0 = (float*)(ws + 87 * MB);
  float* bias1 = bias0 + 128;
  int*   flag  = (int*)(bias1 + 128);
  unsigned short* PB0 = (unsigned short*)(ws + 88 * MB);    // 2.1 MB
  unsigned short* PB1 = (unsigned short*)(ws + 91 * MB);    // 4.2 MB
  unsigned short* L   = (unsigned short*)(ws + 96 * MB);    // 114 KB
  // Corrections in d_out (>=18.9MB): V 8.39 | U 8.39 | T 2.1 (MB, fp32)
  float* V = (float*)d_out;
  float* U = V + (size_t)8 * 32 * 8192;
  float* T = U + (size_t)8 * 32 * 8192;

  dim3 tb(32, 8);
  detect_and_bias<<<1, 256, 0, stream>>>((const unsigned short*)x, mb0, jb0,
                                         mb1, jb1, bias0, bias1, flag);
  build_L<<<N_SLOTS_PAD * 128 / 256, 256, 0, stream>>>(L);
  pack_weights<<<dim3(512, 4, 2), tb, 0, stream>>>(mw0, jw0, mw1, jw1, PB0,
                                                   PB1, flag);
  prep_gemm<<<dim3(128, 7, 2), 256, 0, stream>>>(L, PB0, PB1, Int0, Int1);
  prep_stageB<<<dim3(4, 4, 2 * N_SLOTS), tb, 0, stream>>>(Int0, Int1, Wall0,
                                                          Wall1);
  // x [m*64+f=4096][pos=1024] -> Xt0 [pos][m][f]
  transpose_in<<<dim3(32, 128), tb, 0, stream>>>(
      (const unsigned short*)x, (const float*)x, Xt0, 4096, 1024, flag);

  // ---- Layer 1 (F=64) ----
  corr_gemm<64><<<dim3(576, 2), 256, 0, stream>>>(Xt0, Wall0, V, U, T);
  scan_corr<<<2080, 256, 0, stream>>>(V, U, T);
  final_gemm<64><<<dim3(1024, 2), 256, 0, stream>>>(Xt0, Wall0, V, U, T,
                                                    bias0, A1);
  // ---- Layer 2 (F=128) ----
  corr_gemm<128><<<dim3(576, 2), 256, 0, stream>>>(A1, Wall1, V, U, T);
  scan_corr<<<2080, 256, 0, stream>>>(V, U, T);
  final_gemm<128><<<dim3(1024, 2), 256, 0, stream>>>(A1, Wall1, V, U, T,
                                                     bias1, Out2);

  // Out2 [pos=1024][m*128+g=8192] -> d_out [m][g][pos] (V/U/T dead)
  transpose_out<<<dim3(256, 32), tb, 0, stream>>>(
      Out2, (unsigned short*)d_out, (float*)d_out, 1024, 8192, flag);
}

// Round 8
// 249.656 us; speedup vs baseline: 1.1624x; 1.0902x over previous
//
#include <hip/hip_runtime.h>
#include <stdint.h>

// ---------------------------------------------------------------------------
// LatticeCNN on MI355X — round 8.
//
// Math (validated rounds 2-7):
//   out(x,y) = leaky( X[x,y]·W1[clsx][clsy] + P2 + P3 + P4 + bias )
//   P3 = prefix_a of V[a][y] = X[24+a,y]·AS[a][py]
//   P2 = prefix_b of U[b][x] = X[x,24+b]·SB[px][b]
//   P4 = 2D prefix of T[a][b] = X[24+a,24+b]·mw[a][b]
//   Weight tables are linear maps over the 64 ab-taps:
//   Wall[slot][gf] = sum_k L[slot][k]·PBg[gf][k], K=128=[mw;jw], L closed-form.
//
// Round-7 post-mortem: spill fixed; top-5 all harness d_ws poison fills.
// Residual: 13-dispatch serial chain + Int round-trip (63MB) + fp32
// corrections. Round-8: (1) pack weights in gf-order so prep_gemm stores
// Wall[slot][g][f] directly (Int + stageB deleted); (2) bf16 V/U/T (half
// traffic; also fixes V/U/T overflowing d_out — now in ws); (3) merge
// detect+build_L. 11 dispatches.
//
// Workspace (~88MB of 256MB):
//   Xt0@0 (8.4) | A1@9 (16.8) | Wall0@26 (7.4) | Wall1@34 (14.7)
//   Out2@49 (16.8) | PBg0@66 (2.1) | PBg1@69 (4.2) | L@74 | bias/flag@75
//   V@76 (4.2) | U@81 (4.2) | T@86 (1.05)   (bf16 corrections)
// ---------------------------------------------------------------------------

typedef __attribute__((ext_vector_type(8))) short short8;
typedef __attribute__((ext_vector_type(4))) float floatx4;

__device__ __forceinline__ float bf2f(unsigned short u) {
  union { uint32_t u; float f; } c; c.u = ((uint32_t)u) << 16; return c.f;
}
__device__ __forceinline__ unsigned short f2bf(float f) {
  union { float f; uint32_t u; } c; c.f = f;
  uint32_t u = c.u;
  uint32_t r = (u + 0x7FFFu + ((u >> 16) & 1u)) >> 16;
  return (unsigned short)r;
}

// Weight slot bases inside Wall [slot][G][F]
#define SLOT_W1 0    // 225 combined pointwise slots (clsx*15+clsy)
#define SLOT_SB 225  // 64 slots (px*8+b)
#define SLOT_AS 289  // 64 slots (a*8+py)
#define SLOT_M  353  // 64 slots (a*8+b)
#define N_SLOTS 417
#define N_SLOTS_PAD 448

// Block 0: dtype detect (bf16 flag=0 / fp32 flag=1) + bias build.
// Blocks 1..224: closed-form coefficient matrix L[448][128] bf16.
__global__ __launch_bounds__(256) void setup_kernel(
    const unsigned short* __restrict__ xa,
    const void* __restrict__ mb0, const void* __restrict__ jb0,
    const void* __restrict__ mb1, const void* __restrict__ jb1,
    float* __restrict__ bias0, float* __restrict__ bias1,
    int* __restrict__ flag, unsigned short* __restrict__ L) {
  if (blockIdx.x == 0) {
    __shared__ int cnt;
    if (threadIdx.x == 0) cnt = 0;
    __syncthreads();
    unsigned short v = xa[threadIdx.x];
    int e = (v >> 7) & 0xFF;
    int ok = (v == 0) || (e >= 110 && e <= 140);
    atomicAdd(&cnt, ok);
    __syncthreads();
    int fp32 = (cnt >= 240) ? 0 : 1;
    if (threadIdx.x == 0) *flag = fp32;
    int g = threadIdx.x & 127;
    const void* mb = (threadIdx.x < 128) ? mb0 : mb1;
    const void* jb = (threadIdx.x < 128) ? jb0 : jb1;
    float* bo = (threadIdx.x < 128) ? bias0 : bias1;
    float m = fp32 ? ((const float*)mb)[g] : bf2f(((const unsigned short*)mb)[g]);
    float j = fp32 ? ((const float*)jb)[g] : bf2f(((const unsigned short*)jb)[g]);
    bo[g] = 0.5f * (m + j);
    return;
  }
  int tid = (blockIdx.x - 1) * 256 + threadIdx.x;  // 224*256 = 448*128
  int slot = tid >> 7, k = tid & 127;
  int isj = k >= 64, ab = k & 63, a = ab >> 3, b = ab & 7;
  float v = 0.f;
  if (slot < 225) {
    int cx = slot / 15, cy = slot % 15;
    int pmx = cx < 7 ? cx : 7, pxx = cx > 7 ? cx - 7 : 0;
    int pmy = cy < 7 ? cy : 7, pyy = cy > 7 ? cy - 7 : 0;
    if (!isj) v = (a >= pxx && b >= pyy) ? 0.5f : 0.f;
    else      v = (a <= pmx && b <= pmy) ? 0.5f : 0.f;
  } else if (slot < 289) {
    int s = slot - SLOT_SB, px = s >> 3, b0 = s & 7;
    if (!isj) v = (a >= px && b == b0) ? 0.5f : 0.f;
  } else if (slot < 353) {
    int s = slot - SLOT_AS, a0 = s >> 3, py = s & 7;
    if (!isj) v = (a == a0 && b >= py) ? 0.5f : 0.f;
  } else if (slot < 417) {
    int s = slot - SLOT_M, a0 = s >> 3, b0 = s & 7;
    if (!isj) v = (a == a0 && b == b0) ? 0.5f : 0.f;
  }
  L[tid] = f2bf(v);
}

// Transpose src[R][C] -> dst[C][R]; src fp32 or bf16 per flag, dst bf16.
__global__ __launch_bounds__(256) void transpose_in(
    const unsigned short* __restrict__ s16, const float* __restrict__ s32,
    unsigned short* __restrict__ dst, int R, int C,
    const int* __restrict__ flag) {
  __shared__ unsigned short tile[32][33];
  int fp32 = *flag;
  int tx = threadIdx.x, ty = threadIdx.y;
  int c0 = blockIdx.x * 32, r0 = blockIdx.y * 32;
  if (fp32) {
#pragma unroll
    for (int i = 0; i < 32; i += 8)
      tile[ty + i][tx] = f2bf(s32[(size_t)(r0 + ty + i) * C + (c0 + tx)]);
  } else {
#pragma unroll
    for (int i = 0; i < 32; i += 8)
      tile[ty + i][tx] = s16[(size_t)(r0 + ty + i) * C + (c0 + tx)];
  }
  __syncthreads();
#pragma unroll
  for (int i = 0; i < 32; i += 8)
    dst[(size_t)(c0 + ty + i) * R + (r0 + tx)] = tile[tx][ty + i];
}

// Transpose src[R][C] (bf16) -> dst[C][R]; dst fp32 or bf16 per flag.
__global__ __launch_bounds__(256) void transpose_out(
    const unsigned short* __restrict__ src, unsigned short* __restrict__ d16,
    float* __restrict__ d32, int R, int C, const int* __restrict__ flag) {
  __shared__ unsigned short tile[32][33];
  int fp32 = *flag;
  int tx = threadIdx.x, ty = threadIdx.y;
  int c0 = blockIdx.x * 32, r0 = blockIdx.y * 32;
#pragma unroll
  for (int i = 0; i < 32; i += 8)
    tile[ty + i][tx] = src[(size_t)(r0 + ty + i) * C + (c0 + tx)];
  __syncthreads();
  if (fp32) {
#pragma unroll
    for (int i = 0; i < 32; i += 8)
      d32[(size_t)(c0 + ty + i) * R + (r0 + tx)] = bf2f(tile[tx][ty + i]);
  } else {
#pragma unroll
    for (int i = 0; i < 32; i += 8)
      d16[(size_t)(c0 + ty + i) * R + (r0 + tx)] = tile[tx][ty + i];
  }
}

// Pack mw||jw -> PBg[g*F+f][k=128] bf16 (gf order: f<->g swap via LDS).
// grid (4 g-tiles, 128 f, 2 layers), tb (32,8); layer0 f>=64 blocks exit.
__global__ __launch_bounds__(256) void pack_weights2(
    const void* __restrict__ mw0, const void* __restrict__ jw0,
    const void* __restrict__ mw1, const void* __restrict__ jw1,
    unsigned short* __restrict__ PBg0, unsigned short* __restrict__ PBg1,
    const int* __restrict__ flag) {
  int layer = blockIdx.z;
  int F = layer ? 128 : 64;
  int f = blockIdx.y;
  if (f >= F) return;
  int g0 = blockIdx.x * 32;
  const int G = 128, FG = F * G;
  const void* mw = layer ? mw1 : mw0;
  const void* jw = layer ? jw1 : jw0;
  unsigned short* PB = layer ? PBg1 : PBg0;
  int fp32 = *flag;
  __shared__ unsigned short lds[128][33];
  int tx = threadIdx.x, ty = threadIdx.y;
  for (int k = ty; k < 128; k += 8) {
    const void* src = (k < 64) ? mw : jw;
    int ab = k & 63;
    size_t idx = (size_t)ab * FG + (size_t)f * G + g0 + tx;
    lds[k][tx] = fp32 ? f2bf(((const float*)src)[idx])
                      : ((const unsigned short*)src)[idx];
  }
  __syncthreads();
  int tid = ty * 32 + tx;
  int kk = tid & 127, gs = tid >> 7;  // gs in {0,1}
  for (int gg = gs; gg < 32; gg += 2)
    PB[((size_t)(g0 + gg) * F + f) * 128 + kk] = lds[kk][gg];
}

// MFMA core: acc[64m x (16*NT)g] += A[64m x K] * Wt[g x K]^T (W pre-offset).
// A fragment: lane holds A[m=lane&15][k=(lane>>4)*8+j]   (16B load)
// B fragment: lane holds Wt[n=lane&15][k=(lane>>4)*8+j]  (16B load)
template <int F, int NT>
__device__ __forceinline__ void mfma_tile(
    const unsigned short* __restrict__ A, const unsigned short* __restrict__ W,
    floatx4 acc[NT], int wave, int n, int q) {
  const unsigned short* a_ptr = A + ((size_t)(wave * 16 + n)) * F + q * 8;
  const unsigned short* w_ptr = W + (size_t)n * F + q * 8;
#pragma unroll
  for (int kk = 0; kk < F; kk += 32) {
    short8 av = *(const short8*)(a_ptr + kk);
#pragma unroll
    for (int t = 0; t < NT; ++t) {
      short8 bv = *(const short8*)(w_ptr + (size_t)t * 16 * F + kk);
      acc[t] = __builtin_amdgcn_mfma_f32_16x16x32_bf16(av, bv, acc[t], 0, 0, 0);
    }
  }
}

// Prep GEMM: Wall[slot][gf] = sum_k L[slot][k]*PBg[gf][k]. Direct store.
// grid (n-tiles of 128 gf, 7 m-tiles of 64 slots, 2 layers).
__global__ __launch_bounds__(256) void prep_gemm2(
    const unsigned short* __restrict__ L,
    const unsigned short* __restrict__ PBg0,
    const unsigned short* __restrict__ PBg1,
    unsigned short* __restrict__ Wall0, unsigned short* __restrict__ Wall1) {
  int layer = blockIdx.z;
  int GF = layer ? 16384 : 8192;
  int n0 = blockIdx.x * 128;
  if (n0 >= GF) return;
  int m0 = blockIdx.y * 64;
  const unsigned short* PB = layer ? PBg1 : PBg0;
  unsigned short* Wall = layer ? Wall1 : Wall0;
  int wave = threadIdx.x >> 6, lane = threadIdx.x & 63;
  int n = lane & 15, q = lane >> 4;
  floatx4 acc[8];
#pragma unroll
  for (int t = 0; t < 8; ++t) acc[t] = (floatx4){0.f, 0.f, 0.f, 0.f};
  mfma_tile<128, 8>(L + (size_t)m0 * 128, PB + (size_t)n0 * 128, acc, wave, n, q);
#pragma unroll
  for (int t = 0; t < 8; ++t) {
    int gcol = n0 + t * 16 + n;
#pragma unroll
    for (int r = 0; r < 4; ++r) {
      int m = m0 + wave * 16 + q * 4 + r;  // C/D: row=(lane>>4)*4+reg
      Wall[(size_t)m * GF + gcol] = f2bf(acc[t][r]);
    }
  }
}

// Correction matmuls: grid (576, 2); gs = g-half. bf16 stores.
//   bid <256 : V[a][y] = X[24+a, y]      * AS[a][py(y)]
//   bid <512 : U[b][x] = X[x, 24+b]      * SB[px(x)][b]
//   else     : T[a][b] = X[24+a, 24+b]   * mw[a][b]
template <int F>
__global__ __launch_bounds__(256) void corr_gemm(
    const unsigned short* __restrict__ Xt, const unsigned short* __restrict__ Wall,
    unsigned short* __restrict__ V, unsigned short* __restrict__ U,
    unsigned short* __restrict__ T) {
  int bid = blockIdx.x, gs = blockIdx.y;
  int wave = threadIdx.x >> 6, lane = threadIdx.x & 63;
  int n = lane & 15, q = lane >> 4;
  int ipos, slot;
  unsigned short* out;
  if (bid < 256) {
    int a = bid >> 5, y = bid & 31;
    int py = y > 24 ? y - 24 : 0;
    ipos = (24 + a) * 32 + y;
    slot = SLOT_AS + a * 8 + py;
    out = V + (size_t)(a * 32 + y) * 8192;
  } else if (bid < 512) {
    int i = bid - 256;
    int b = i >> 5, x = i & 31;
    int px = x > 24 ? x - 24 : 0;
    ipos = x * 32 + 24 + b;
    slot = SLOT_SB + px * 8 + b;
    out = U + (size_t)(b * 32 + x) * 8192;
  } else {
    int i = bid - 512;
    int a = i >> 3, b = i & 7;
    ipos = (24 + a) * 32 + 24 + b;
    slot = SLOT_M + a * 8 + b;
    out = T + (size_t)(a * 8 + b) * 8192;
  }
  floatx4 acc[4];
#pragma unroll
  for (int t = 0; t < 4; ++t) acc[t] = (floatx4){0.f, 0.f, 0.f, 0.f};
  mfma_tile<F, 4>(Xt + (size_t)ipos * 64 * F,
                  Wall + ((size_t)slot * 128 + gs * 64) * F, acc, wave, n, q);
#pragma unroll
  for (int t = 0; t < 4; ++t) {
    int gcol = gs * 64 + t * 16 + n;
#pragma unroll
    for (int r = 0; r < 4; ++r) {
      int m = wave * 16 + q * 4 + r;
      out[(size_t)m * 128 + gcol] = f2bf(acc[t][r]);
    }
  }
}

// In-place prefix scans (bf16 storage, fp32 accumulate):
// [0,1024) P3 over V (a); [1024,2048) P2 over U (b); [2048,2080) 2D over T.
__global__ __launch_bounds__(256) void scan_corr(unsigned short* __restrict__ V,
                                                 unsigned short* __restrict__ U,
                                                 unsigned short* __restrict__ T) {
  int b = blockIdx.x;
  if (b < 2048) {
    unsigned short* base = (b < 1024) ? V : U;
    int tid = ((b & 1023) * 256 + threadIdx.x);  // (y|x, mg): 262144
    unsigned short* p = base + (size_t)tid;      // stride 262144 over a|b
    float s = 0.f;
#pragma unroll
    for (int a = 0; a < 8; ++a) {
      s += bf2f(p[(size_t)a * 262144]);
      p[(size_t)a * 262144] = f2bf(s);
    }
  } else {
    int mg = (b - 2048) * 256 + threadIdx.x;  // 8192
    float col[8];
#pragma unroll
    for (int i = 0; i < 8; ++i) col[i] = 0.f;
#pragma unroll
    for (int a = 0; a < 8; ++a) {
      float rs = 0.f;
#pragma unroll
      for (int bb = 0; bb < 8; ++bb) {
        size_t idx = (size_t)(a * 8 + bb) * 8192 + mg;
        col[bb] += bf2f(T[idx]);
        rs += col[bb];
        T[idx] = f2bf(rs);
      }
    }
  }
}

// term1 + corrections + bias + leaky-relu -> bf16 [pos][m][128].
// grid (1024, 2); gs = g-half. Correction/bias loads hoisted before MFMA.
template <int F>
__global__ __launch_bounds__(256) void final_gemm(
    const unsigned short* __restrict__ Xt, const unsigned short* __restrict__ Wall,
    const unsigned short* __restrict__ V, const unsigned short* __restrict__ U,
    const unsigned short* __restrict__ T, const float* __restrict__ bias,
    unsigned short* __restrict__ Out) {
  int pos = blockIdx.x, gs = blockIdx.y;
  int x = pos >> 5, y = pos & 31;
  int wave = threadIdx.x >> 6, lane = threadIdx.x & 63;
  int n = lane & 15, q = lane >> 4;
  int clsx = x < 7 ? x : (x <= 24 ? 7 : x - 17);
  int clsy = y < 7 ? y : (y <= 24 ? 7 : y - 17);
  int px = x > 24 ? x - 24 : 0;
  int py = y > 24 ? y - 24 : 0;
  const unsigned short* c3 = px ? V + ((size_t)(px - 1) * 32 + y) * 8192 : nullptr;
  const unsigned short* c2 = py ? U + ((size_t)(py - 1) * 32 + x) * 8192 : nullptr;
  const unsigned short* c4 =
      (px && py) ? T + (size_t)((px - 1) * 8 + (py - 1)) * 8192 : nullptr;

  // Hoisted bias + correction sum (loads overlap the MFMA-loop loads).
  float csum[4][4];
#pragma unroll
  for (int t = 0; t < 4; ++t) {
    int gcol = gs * 64 + t * 16 + n;
    float bv = bias[gcol];
#pragma unroll
    for (int r = 0; r < 4; ++r) {
      int m = wave * 16 + q * 4 + r;
      size_t idx = (size_t)m * 128 + gcol;
      float v = bv;
      if (c3) v += bf2f(c3[idx]);
      if (c2) v += bf2f(c2[idx]);
      if (c4) v += bf2f(c4[idx]);
      csum[t][r] = v;
    }
  }

  floatx4 acc[4];
#pragma unroll
  for (int t = 0; t < 4; ++t) acc[t] = (floatx4){0.f, 0.f, 0.f, 0.f};
  mfma_tile<F, 4>(Xt + (size_t)pos * 64 * F,
                  Wall + ((size_t)(SLOT_W1 + clsx * 15 + clsy) * 128 + gs * 64) * F,
                  acc, wave, n, q);

  unsigned short* o = Out + (size_t)pos * 64 * 128;
#pragma unroll
  for (int t = 0; t < 4; ++t) {
    int gcol = gs * 64 + t * 16 + n;
#pragma unroll
    for (int r = 0; r < 4; ++r) {
      int m = wave * 16 + q * 4 + r;  // C/D layout: row=(lane>>4)*4+reg
      float v = acc[t][r] + csum[t][r];
      v = v > 0.f ? v : 0.01f * v;
      o[(size_t)m * 128 + gcol] = f2bf(v);
    }
  }
}

extern "C" void kernel_launch(void* const* d_in, const int* in_sizes, int n_in,
                              void* d_out, int out_size, void* d_ws,
                              size_t ws_size, hipStream_t stream) {
  const void* x   = d_in[0];
  const void* mw0 = d_in[5];
  const void* mb0 = d_in[6];
  const void* jw0 = d_in[7];
  const void* jb0 = d_in[8];
  const void* mw1 = d_in[9];
  const void* mb1 = d_in[10];
  const void* jw1 = d_in[11];
  const void* jb1 = d_in[12];

  char* ws = (char*)d_ws;
  const size_t MB = 1u << 20;
  unsigned short* Xt0   = (unsigned short*)(ws + 0);        // 8.4 MB
  unsigned short* A1    = (unsigned short*)(ws + 9 * MB);   // 16.8 MB
  unsigned short* Wall0 = (unsigned short*)(ws + 26 * MB);  // 7.4 MB (448)
  unsigned short* Wall1 = (unsigned short*)(ws + 34 * MB);  // 14.7 MB (448)
  unsigned short* Out2  = (unsigned short*)(ws + 49 * MB);  // 16.8 MB
  unsigned short* PBg0  = (unsigned short*)(ws + 66 * MB);  // 2.1 MB
  unsigned short* PBg1  = (unsigned short*)(ws + 69 * MB);  // 4.2 MB
  unsigned short* L     = (unsigned short*)(ws + 74 * MB);  // 114 KB
  float* bias0 = (float*)(ws + 75 * MB);
  float* bias1 = bias0 + 128;
  int*   flag  = (int*)(bias1 + 128);
  unsigned short* V = (unsigned short*)(ws + 76 * MB);      // 4.2 MB
  unsigned short* U = (unsigned short*)(ws + 81 * MB);      // 4.2 MB
  unsigned short* T = (unsigned short*)(ws + 86 * MB);      // 1.05 MB

  dim3 tb(32, 8);
  setup_kernel<<<225, 256, 0, stream>>>((const unsigned short*)x, mb0, jb0,
                                        mb1, jb1, bias0, bias1, flag, L);
  pack_weights2<<<dim3(4, 128, 2), tb, 0, stream>>>(mw0, jw0, mw1, jw1, PBg0,
                                                    PBg1, flag);
  prep_gemm2<<<dim3(128, 7, 2), 256, 0, stream>>>(L, PBg0, PBg1, Wall0, Wall1);
  // x [m*64+f=4096][pos=1024] -> Xt0 [pos][m][f]
  transpose_in<<<dim3(32, 128), tb, 0, stream>>>(
      (const unsigned short*)x, (const float*)x, Xt0, 4096, 1024, flag);

  // ---- Layer 1 (F=64) ----
  corr_gemm<64><<<dim3(576, 2), 256, 0, stream>>>(Xt0, Wall0, V, U, T);
  scan_corr<<<2080, 256, 0, stream>>>(V, U, T);
  final_gemm<64><<<dim3(1024, 2), 256, 0, stream>>>(Xt0, Wall0, V, U, T,
                                                    bias0, A1);
  // ---- Layer 2 (F=128) ----
  corr_gemm<128><<<dim3(576, 2), 256, 0, stream>>>(A1, Wall1, V, U, T);
  scan_corr<<<2080, 256, 0, stream>>>(V, U, T);
  final_gemm<128><<<dim3(1024, 2), 256, 0, stream>>>(A1, Wall1, V, U, T,
                                                     bias1, Out2);

  // Out2 [pos=1024][m*128+g=8192] -> d_out [m][g][pos]
  transpose_out<<<dim3(256, 32), tb, 0, stream>>>(
      Out2, (unsigned short*)d_out, (float*)d_out, 1024, 8192, flag);
}